// Round 13
// baseline (277.015 us; speedup 1.0000x reference)
//
#include <hip/hip_runtime.h>

#define N_NODES 20000
#define E_EDGES 640000
#define R_REL   64
#define B_BASES 16
#define NSEG    128                  // edge segments
#define SEGLEN  (E_EDGES / NSEG)     // 5000
#define RH      10000                // node half-range (LDS histogram bins)
#define NBPR    32                   // blocks per relation in k_edge_mfma
#define QG      ((2 * NSEG) / 16)    // he-entries per scan group = 16

// k_prep block ranges
#define PB_WREL (R_REL * 16)         // 1024 wt_h blocks
#define PB_LW   (PB_WREL + 16)       // +16 lwT blocks
#define PB_XH   (PB_LW + 2500)       // +2500 xhalf blocks (exact)
#define PB_HIST (PB_XH + 2 * NSEG)   // +256 hist blocks

#define SELF_B  ((N_NODES + 63) / 64)   // 313

typedef __attribute__((ext_vector_type(4))) float f32x4;
typedef __attribute__((ext_vector_type(8))) _Float16 half8;
typedef __attribute__((ext_vector_type(4))) unsigned int u32x4;

__device__ inline float h2f(unsigned short v) {
    _Float16 h; __builtin_memcpy(&h, &v, 2); return (float)h;
}
__device__ inline unsigned short f2h(float f) {
    _Float16 h = (_Float16)f; unsigned short v; __builtin_memcpy(&v, &h, 2); return v;
}

__device__ inline void gld_lds16(const void* g, void* l) {
    __builtin_amdgcn_global_load_lds(
        (const __attribute__((address_space(1))) void*)g,
        (__attribute__((address_space(3))) void*)l, 16, 0, 0);
}

// ======================= big-path precompute (fused) =======================
// [0,1024): wt_h[r][o][i] = f16(sum_b w_comp[r,b]*weight[b][i][o])
// [1024,1040): lwT[o][i] = f16(loop_w[i][o])
// [1040,3540): xh = f16(x)
// [3540,3796): per-(seg,half) dst hist (ushort) + etype hist
__global__ void k_prep(const float* weight, const float* w_comp, unsigned short* wt_h,
                       const float* lw, unsigned short* lwT,
                       const float* x, unsigned short* xh,
                       const int* etypes, const int* dst,
                       unsigned short* hps, int* he)
{
    __shared__ float tile[32][33];
    __shared__ float wcS[B_BASES];
    __shared__ int lh[RH];
    __shared__ int heL[R_REL];
    int b = blockIdx.x, t = threadIdx.x;
    int tx = t & 31, ty = t >> 5;   // 32 x 8

    if (b < PB_WREL) {
        int r  = b >> 4;
        int ti = (b >> 2) & 3;
        int tj = b & 3;
        if (t < B_BASES) wcS[t] = w_comp[r * B_BASES + t];
        __syncthreads();
        float acc[4] = {0.f, 0.f, 0.f, 0.f};
        const float* wp = weight + (ti * 32) * 128 + tj * 32;
        for (int bb = 0; bb < B_BASES; bb++) {
            float c = wcS[bb];
            #pragma unroll
            for (int s = 0; s < 4; s++)
                acc[s] += c * wp[bb * 16384 + (ty + s * 8) * 128 + tx];
        }
        #pragma unroll
        for (int s = 0; s < 4; s++) tile[ty + s * 8][tx] = acc[s];
        __syncthreads();
        unsigned short* dstp = wt_h + r * 16384 + (tj * 32) * 128 + ti * 32;
        #pragma unroll
        for (int s = 0; s < 4; s++)
            dstp[(ty + s * 8) * 128 + tx] = f2h(tile[tx][ty + s * 8]);
        return;
    }
    if (b < PB_LW) {
        int q = b - PB_WREL;
        int ti = q >> 2, tj = q & 3;
        const float* srcp = lw + (ti * 32) * 128 + tj * 32;
        #pragma unroll
        for (int s = 0; s < 4; s++)
            tile[ty + s * 8][tx] = srcp[(ty + s * 8) * 128 + tx];
        __syncthreads();
        unsigned short* d = lwT + (tj * 32) * 128 + ti * 32;
        #pragma unroll
        for (int s = 0; s < 4; s++)
            d[(ty + s * 8) * 128 + tx] = f2h(tile[tx][ty + s * 8]);
        return;
    }
    if (b < PB_XH) {
        int i4 = (b - PB_LW) * 256 + t;    // exact: 2500*256 = N*128/4
        float4 v = ((const float4*)x)[i4];
        ushort4 o;
        o.x = f2h(v.x); o.y = f2h(v.y); o.z = f2h(v.z); o.w = f2h(v.w);
        ((ushort4*)xh)[i4] = o;
        return;
    }
    // histogram blocks
    {
        int q = b - PB_XH;
        int s = q >> 1, h = q & 1;
        for (int i = t; i < RH; i += 256) lh[i] = 0;
        if (t < R_REL) heL[t] = 0;
        __syncthreads();
        int e0 = s * SEGLEN;
        for (int k = t; k < SEGLEN; k += 256) {
            int e = e0 + k;
            int d = dst[e];
            unsigned ld = (unsigned)(d - h * RH);
            if (ld < RH) {
                atomicAdd(&lh[ld], 1);
                atomicAdd(&heL[etypes[e]], 1);
            }
        }
        __syncthreads();
        for (int i = t; i < RH; i += 256)
            hps[(size_t)s * N_NODES + h * RH + i] = (unsigned short)lh[i];
        if (t < R_REL) he[q * 64 + t] = heL[t];
    }
}

// fused: hps[s][n] -> within-node exclusive prefix (ushort), counts2[n] = total
__global__ void k_sumseg(unsigned short* hps, int* counts2)
{
    int n = blockIdx.x * 256 + threadIdx.x;
    if (n >= N_NODES) return;
    int run = 0;
    for (int q = 0; q < NSEG; q += 8) {
        int v[8];
        #pragma unroll
        for (int k = 0; k < 8; k++) v[k] = hps[(size_t)(q + k) * N_NODES + n];
        #pragma unroll
        for (int k = 0; k < 8; k++) {
            hps[(size_t)(q + k) * N_NODES + n] = (unsigned short)run;
            run += v[k];
        }
    }
    counts2[n] = run;
}

// single block 1024: PARALLEL etype scan + be fill, plus off2 scan (from counts2)
__global__ void k_scan_all2(const int* he, const int* counts2,
                            int* offsets, int* off2, int* be)
{
    __shared__ int part[1024];
    __shared__ int psum[16][R_REL];
    __shared__ int offL[R_REL];
    int tid = threadIdx.x;
    int t = tid & 63;          // etype
    int g = tid >> 6;          // group 0..15
    int vals[QG];
    int ps = 0;
    #pragma unroll
    for (int k = 0; k < QG; k++) {
        vals[k] = he[(g * QG + k) * 64 + t];
        ps += vals[k];
    }
    psum[g][t] = ps;
    __syncthreads();
    if (tid < 64) {
        int c = 0;
        #pragma unroll
        for (int gg = 0; gg < 16; gg++) c += psum[gg][t];
        int s1 = c;
        for (int d = 1; d < 64; d <<= 1) {
            int a1 = __shfl_up(s1, d);
            if (t >= d) s1 += a1;
        }
        offsets[t] = s1 - c;
        offL[t] = s1 - c;
        if (t == 63) offsets[64] = s1;
    }
    __syncthreads();
    {
        int run = offL[t];
        for (int gg = 0; gg < g; gg++) run += psum[gg][t];
        #pragma unroll
        for (int k = 0; k < QG; k++) {
            be[(g * QG + k) * 64 + t] = run;
            run += vals[k];
        }
    }
    int lo_i = tid * 20, hi_i = lo_i + 20;
    if (hi_i > N_NODES) hi_i = N_NODES;
    if (lo_i > N_NODES) lo_i = N_NODES;
    int s = 0;
    for (int i = lo_i; i < hi_i; i++) s += counts2[i];
    part[tid] = s;
    __syncthreads();
    for (int d = 1; d < 1024; d <<= 1) {
        int v = (tid >= d) ? part[tid - d] : 0;
        __syncthreads();
        part[tid] += v;
        __syncthreads();
    }
    int run = part[tid] - s;
    for (int i = lo_i; i < hi_i; i++) {
        off2[i] = run;
        run += counts2[i];
    }
    if (tid == 1023) off2[N_NODES] = run;
}

// per-(seg,half): lbase = off2[n] + pref ; LDS-atomic slot + p assignment
__global__ void k_scatter3(const int* etypes, const int* dst, const int* src, const float* norm,
                           const unsigned short* hps, const int* be, const int* off2,
                           int* perm_src, float* pnorm, int* pos2)
{
    __shared__ int lbase[RH];
    __shared__ int ebase[R_REL];
    int t = threadIdx.x, q = blockIdx.x;
    int s = q >> 1, h = q & 1;
    for (int i = t; i < RH; i += 256)
        lbase[i] = off2[h * RH + i] + (int)hps[(size_t)s * N_NODES + h * RH + i];
    if (t < R_REL) ebase[t] = be[q * 64 + t];
    __syncthreads();
    int e0 = s * SEGLEN;
    for (int k = t; k < SEGLEN; k += 256) {
        int e = e0 + k;
        int d = dst[e];
        unsigned ld = (unsigned)(d - h * RH);
        if (ld < RH) {
            int slot = atomicAdd(&lbase[ld], 1);
            int p = atomicAdd(&ebase[etypes[e]], 1);
            perm_src[p] = src[e];
            pnorm[p] = norm[e];
            pos2[p] = slot;
        }
    }
}

// ---- Phase A (fused): edge blocks [0, R_REL*NBPR) + self blocks after.
//      1 wave = 16 rows x 128 cols, depth-2 pipeline,
//      16B permuted NON-TEMPORAL stores (c'=lr*8+n). ----
__global__ __launch_bounds__(256) void k_edge_mfma(
    const unsigned short* __restrict__ xh, const unsigned short* __restrict__ wt_h,
    const unsigned short* __restrict__ lwT,
    const int* __restrict__ perm_src, const float* __restrict__ pnorm,
    const int* __restrict__ pos2, const int* __restrict__ offsets,
    unsigned short* __restrict__ msg, float* __restrict__ out)
{
    __shared__ __align__(16) char smemW[32768];   // W: [o=128][16 chunks of 8 f16], swizzled
    int t = threadIdx.x, b = blockIdx.x;
    int l = t & 63, w = t >> 6;
    int lg = l >> 4, lr = l & 15;
    const half8* smW = (const half8*)smemW;

    if (b >= R_REL * NBPR) {
        // ---- self-loop tile ----
        int n0 = (b - R_REL * NBPR) * 64;
        #pragma unroll
        for (int it = 0; it < 8; it++) {
            int s = it * 256 + t;
            int o = s >> 4, ch = s & 15;
            int jx = ch ^ (o & 15);
            gld_lds16(lwT + o * 128 + jx * 8, smemW + s * 16);
        }
        int rowA = w * 16 + lr;
        int nA = n0 + rowA; if (nA >= N_NODES) nA = N_NODES - 1;
        const half8* xr = (const half8*)(xh + (size_t)nA * 128);
        half8 avC[4];
        #pragma unroll
        for (int kk = 0; kk < 4; kk++) avC[kk] = xr[kk * 4 + lg];
        f32x4 acc[8];
        #pragma unroll
        for (int n = 0; n < 8; n++) acc[n] = {0.0f, 0.0f, 0.0f, 0.0f};
        __syncthreads();
        #pragma unroll
        for (int kk = 0; kk < 4; kk++) {
            #pragma unroll
            for (int n = 0; n < 8; n++) {
                int o = n * 16 + lr;
                half8 bv = smW[o * 16 + ((kk * 4 + lg) ^ (o & 15))];
                acc[n] = __builtin_amdgcn_mfma_f32_16x16x32_f16(avC[kk], bv, acc[n], 0, 0, 0);
            }
        }
        #pragma unroll
        for (int jj = 0; jj < 4; jj++) {
            int row = w * 16 + lg * 4 + jj;
            int n = n0 + row;
            if (n < N_NODES) {
                float4 v0, v1;
                v0.x = acc[0][jj]; v0.y = acc[1][jj]; v0.z = acc[2][jj]; v0.w = acc[3][jj];
                v1.x = acc[4][jj]; v1.y = acc[5][jj]; v1.z = acc[6][jj]; v1.w = acc[7][jj];
                *(float4*)(out + (size_t)n * 128 + lr * 8) = v0;
                *(float4*)(out + (size_t)n * 128 + lr * 8 + 4) = v1;
            }
        }
        return;
    }

    // ---- edge blocks ----
    int r = b >> 5;              // NBPR = 32
    int j = b & (NBPR - 1);
    int p0 = offsets[r], p1 = offsets[r + 1];
    int nch = (p1 - p0 + 63) >> 6;

    {
        const size_t rbase = (size_t)r * 16384;
        #pragma unroll
        for (int it = 0; it < 8; it++) {
            int s = it * 256 + t;
            int o = s >> 4, ch = s & 15;
            int jx = ch ^ (o & 15);
            gld_lds16(wt_h + rbase + o * 128 + jx * 8, smemW + s * 16);
        }
    }

    int rowA = w * 16 + lr;

    int i = j;
    int sN = 0;
    if (i < nch) {
        int e0 = p0 + i * 64;
        int cnt = p1 - e0; if (cnt > 64) cnt = 64;
        sN = (rowA < cnt) ? perm_src[e0 + rowA] : 0;
    }

    __syncthreads();     // W resident

    half8 avC[4];
    {
        const half8* xr = (const half8*)(xh + (size_t)sN * 128);
        #pragma unroll
        for (int kk = 0; kk < 4; kk++) avC[kk] = xr[kk * 4 + lg];
    }
    int i2 = i + NBPR;
    if (i2 < nch) {
        int e0 = p0 + i2 * 64;
        int cnt = p1 - e0; if (cnt > 64) cnt = 64;
        sN = (rowA < cnt) ? perm_src[e0 + rowA] : 0;
    }

    while (i < nch) {
        int e0 = p0 + i * 64;
        int cnt = p1 - e0; if (cnt > 64) cnt = 64;

        int slotC[4]; float nrmC[4];
        #pragma unroll
        for (int jj = 0; jj < 4; jj++) {
            int row = w * 16 + lg * 4 + jj;
            bool vld = row < cnt;
            slotC[jj] = vld ? pos2[e0 + row] : -1;
            nrmC[jj]  = vld ? pnorm[e0 + row] : 0.0f;
        }

        half8 avN[4];
        {
            const half8* xr = (const half8*)(xh + (size_t)sN * 128);
            #pragma unroll
            for (int kk = 0; kk < 4; kk++) avN[kk] = xr[kk * 4 + lg];
        }
        int i3 = i2 + NBPR;
        if (i3 < nch) {
            int e0n = p0 + i3 * 64;
            int cntn = p1 - e0n; if (cntn > 64) cntn = 64;
            sN = (rowA < cntn) ? perm_src[e0n + rowA] : 0;
        }

        f32x4 acc[8];
        #pragma unroll
        for (int n = 0; n < 8; n++) acc[n] = {0.0f, 0.0f, 0.0f, 0.0f};

        #pragma unroll
        for (int kk = 0; kk < 4; kk++) {
            #pragma unroll
            for (int n = 0; n < 8; n++) {
                int o = n * 16 + lr;
                half8 bv = smW[o * 16 + ((kk * 4 + lg) ^ (o & 15))];
                acc[n] = __builtin_amdgcn_mfma_f32_16x16x32_f16(avC[kk], bv, acc[n], 0, 0, 0);
            }
        }

        #pragma unroll
        for (int jj = 0; jj < 4; jj++) {
            int slot = slotC[jj];
            if (slot >= 0) {
                float nm = nrmC[jj];
                u32x4 ov;
                ov.x = (unsigned int)f2h(acc[0][jj] * nm) | ((unsigned int)f2h(acc[1][jj] * nm) << 16);
                ov.y = (unsigned int)f2h(acc[2][jj] * nm) | ((unsigned int)f2h(acc[3][jj] * nm) << 16);
                ov.z = (unsigned int)f2h(acc[4][jj] * nm) | ((unsigned int)f2h(acc[5][jj] * nm) << 16);
                ov.w = (unsigned int)f2h(acc[6][jj] * nm) | ((unsigned int)f2h(acc[7][jj] * nm) << 16);
                __builtin_nontemporal_store(ov, (u32x4*)(msg + (size_t)slot * 128 + lr * 8));
            }
        }

        #pragma unroll
        for (int kk = 0; kk < 4; kk++) avC[kk] = avN[kk];
        i = i2; i2 = i3;
    }
}

// ---- msg reduction: 1 wave per node, no barriers/LDS. Lane c owns permuted cols {2c,2c+1}.
//      Non-temporal msg loads (single-touch); self-add from permuted out row;
//      in-register un-permute (nc1 = nc0+16); bias + relu; 4B scattered stores. ----
__global__ __launch_bounds__(256) void k_msgsum(const unsigned short* __restrict__ msg,
                                                const int* __restrict__ off2,
                                                const float* __restrict__ bias,
                                                float* __restrict__ out)
{
    int t = threadIdx.x;
    int wv = t >> 6, c = t & 63;
    int n = blockIdx.x * 4 + wv;
    if (n >= N_NODES) return;
    int m0 = off2[n], m1 = off2[n + 1];
    float a0 = 0.0f, a1 = 0.0f;
    int j = m0;
    for (; j + 4 <= m1; j += 4) {
        unsigned v0 = __builtin_nontemporal_load((const unsigned*)(msg + (size_t)(j + 0) * 128 + c * 2));
        unsigned v1 = __builtin_nontemporal_load((const unsigned*)(msg + (size_t)(j + 1) * 128 + c * 2));
        unsigned v2 = __builtin_nontemporal_load((const unsigned*)(msg + (size_t)(j + 2) * 128 + c * 2));
        unsigned v3 = __builtin_nontemporal_load((const unsigned*)(msg + (size_t)(j + 3) * 128 + c * 2));
        a0 += h2f((unsigned short)(v0 & 0xffff)) + h2f((unsigned short)(v1 & 0xffff))
            + h2f((unsigned short)(v2 & 0xffff)) + h2f((unsigned short)(v3 & 0xffff));
        a1 += h2f((unsigned short)(v0 >> 16)) + h2f((unsigned short)(v1 >> 16))
            + h2f((unsigned short)(v2 >> 16)) + h2f((unsigned short)(v3 >> 16));
    }
    for (; j < m1; j++) {
        unsigned v = __builtin_nontemporal_load((const unsigned*)(msg + (size_t)j * 128 + c * 2));
        a0 += h2f((unsigned short)(v & 0xffff));
        a1 += h2f((unsigned short)(v >> 16));
    }
    float2 o = *(const float2*)(out + (size_t)n * 128 + c * 2);   // self (permuted)
    a0 += o.x; a1 += o.y;
    int cp0 = c * 2;
    int nc0 = (cp0 & 7) * 16 + (cp0 >> 3);    // natural col; cp1 -> nc0 + 16
    a0 += bias[nc0]; a1 += bias[nc0 + 16];
    if (a0 < 0.0f) a0 = 0.0f;
    if (a1 < 0.0f) a1 = 0.0f;
    // wave-lockstep: all reads of this row (load instrs above) precede these stores
    out[(size_t)n * 128 + nc0]      = a0;
    out[(size_t)n * 128 + nc0 + 16] = a1;
}

// ======================= fallback path (small ws) =======================

__global__ void k_wrel(const float* weight, const float* w_comp, float* W_rel)
{
    int idx = blockIdx.x * 256 + threadIdx.x;
    int r  = idx >> 14;
    int io = idx & 16383;
    float acc = 0.0f;
    for (int b = 0; b < B_BASES; b++)
        acc += w_comp[r * B_BASES + b] * weight[b * 16384 + io];
    W_rel[idx] = acc;
}

__global__ void k_zero(float* agg, int* counts, int* counts2)
{
    int idx = blockIdx.x * 256 + threadIdx.x;
    if (idx < N_NODES * 128) agg[idx] = 0.0f;
    if (idx < R_REL) counts[idx] = 0;
    if (idx < N_NODES) counts2[idx] = 0;
}

__global__ void k_hist(const int* etypes, int* counts)
{
    __shared__ int h[R_REL];
    int t = threadIdx.x;
    if (t < R_REL) h[t] = 0;
    __syncthreads();
    int e = blockIdx.x * 256 + t;
    atomicAdd(&h[etypes[e]], 1);
    __syncthreads();
    if (t < R_REL && h[t] != 0) atomicAdd(&counts[t], h[t]);
}

__global__ void k_scan(const int* counts, int* offsets, int* cursor, int* co)
{
    if (threadIdx.x == 0) {
        int run = 0, c = 0;
        for (int r = 0; r < R_REL; r++) {
            offsets[r] = run; cursor[r] = run; co[r] = c;
            run += counts[r];
            c   += (counts[r] + 63) >> 6;
        }
        offsets[R_REL] = run; co[R_REL] = c;
    }
}

__global__ void k_scatter(const int* etypes, int* cursor, int* perm)
{
    __shared__ int h[R_REL];
    __shared__ int base[R_REL];
    int t = threadIdx.x;
    if (t < R_REL) h[t] = 0;
    __syncthreads();
    int e = blockIdx.x * 256 + t;
    int et = etypes[e];
    int rank = atomicAdd(&h[et], 1);
    __syncthreads();
    if (t < R_REL && h[t] != 0) base[t] = atomicAdd(&cursor[t], h[t]);
    __syncthreads();
    perm[base[et] + rank] = e;
}

__global__ void k_edge_atomic(const float* x, const float* W_rel, const float* norm,
                              const int* src, const int* dst, const int* perm,
                              const int* offsets, const int* co, float* agg)
{
    __shared__ float4 WfS[2048];
    __shared__ float4 xsS[1024];
    __shared__ int coS[R_REL + 1];
    __shared__ int srcS[64], dstS[64];
    __shared__ float normS[64];
    int t = threadIdx.x, bid = blockIdx.x;
    if (t <= R_REL) coS[t] = co[t];
    __syncthreads();
    if (bid >= coS[R_REL]) return;
    int r = 0;
    while (bid >= coS[r + 1]) r++;
    int e0 = offsets[r] + (bid - coS[r]) * 64;
    int cnt = offsets[r + 1] - e0;
    if (cnt > 64) cnt = 64;
    if (t < 64) {
        if (t < cnt) {
            int eid = perm[e0 + t];
            srcS[t] = src[eid]; dstS[t] = dst[eid]; normS[t] = norm[eid];
        } else { srcS[t] = 0; dstS[t] = 0; normS[t] = 0.0f; }
    }
    const float* xsf = (const float*)xsS;
    int q  = t & 31;
    int eb = t >> 5;
    float4 acc[8];
    for (int k = 0; k < 8; k++) { acc[k].x = 0.f; acc[k].y = 0.f; acc[k].z = 0.f; acc[k].w = 0.f; }
    for (int h = 0; h < 2; h++) {
        __syncthreads();
        const float4* Wsrc = (const float4*)(W_rel + r * 16384 + h * 8192);
        for (int p = 0; p < 8; p++) WfS[p * 256 + t] = Wsrc[p * 256 + t];
        for (int p = 0; p < 4; p++) {
            int idx = p * 256 + t;
            int e = idx >> 4, c = idx & 15;
            xsS[idx] = ((const float4*)(x + srcS[e] * 128 + h * 64))[c];
        }
        __syncthreads();
        for (int i = 0; i < 64; i++) {
            float4 wv = WfS[i * 32 + q];
            for (int k = 0; k < 8; k++) {
                float xv = xsf[(eb + 8 * k) * 64 + i];
                acc[k].x += xv * wv.x;
                acc[k].y += xv * wv.y;
                acc[k].z += xv * wv.z;
                acc[k].w += xv * wv.w;
            }
        }
    }
    for (int k = 0; k < 8; k++) {
        int e = eb + 8 * k;
        if (e < cnt) {
            float nrm = normS[e];
            float* row = agg + dstS[e] * 128 + q * 4;
            atomicAdd(row + 0, acc[k].x * nrm);
            atomicAdd(row + 1, acc[k].y * nrm);
            atomicAdd(row + 2, acc[k].z * nrm);
            atomicAdd(row + 3, acc[k].w * nrm);
        }
    }
}

__global__ void k_out(const float* x, const float* loop_w, const float* agg,
                      const float* bias, float* out)
{
    __shared__ float xrow[128];
    int n = blockIdx.x;
    int o = threadIdx.x;
    xrow[o] = x[n * 128 + o];
    __syncthreads();
    float acc = 0.0f;
    for (int i = 0; i < 128; i++)
        acc += xrow[i] * loop_w[i * 128 + o];
    float val = acc + agg[n * 128 + o] + bias[o];
    if (val < 0.0f) val = 0.0f;
    out[n * 128 + o] = val;
}

extern "C" void kernel_launch(void* const* d_in, const int* in_sizes, int n_in,
                              void* d_out, int out_size, void* d_ws, size_t ws_size,
                              hipStream_t stream)
{
    const float* x      = (const float*)d_in[0];
    const float* weight = (const float*)d_in[1];
    const float* w_comp = (const float*)d_in[2];
    const float* h_bias = (const float*)d_in[3];
    const float* loop_w = (const float*)d_in[4];
    const float* norm   = (const float*)d_in[5];
    const int* src    = (const int*)d_in[6];
    const int* dst    = (const int*)d_in[7];
    const int* etypes = (const int*)d_in[8];
    float* out = (float*)d_out;

    char* ws = (char*)d_ws;
    size_t off = 0;
    float* W_rel = (float*)(ws + off); off += (size_t)R_REL * 16384 * 4;      // big: wt_h (2MB) + lwT in 4MB
    float* agg   = (float*)(ws + off); off += (size_t)N_NODES * 128 * 4;      // big: xh (5MB) + pnorm (2.5MB) in 10MB
    int* perm    = (int*)(ws + off);   off += (size_t)E_EDGES * 4;            // big: perm_src
    int* counts  = (int*)(ws + off);   off += 64 * 4;
    int* offsets = (int*)(ws + off);   off += 68 * 4;
    int* cursor  = (int*)(ws + off);   off += 64 * 4;
    int* co      = (int*)(ws + off);   off += 68 * 4;
    int* counts2 = (int*)(ws + off);   off += (size_t)N_NODES * 4;
    int* off2    = (int*)(ws + off);   off += (size_t)(N_NODES + 4) * 4;      // padded to keep 16B align
    int* cursor2 = (int*)(ws + off);   off += (size_t)N_NODES * 4;
    int* pos2    = (int*)(ws + off);   off += (size_t)E_EDGES * 4;
    unsigned short* msg = (unsigned short*)(ws + off);
    size_t need_big = off + (size_t)E_EDGES * 128 * 2;
    int big = (ws_size >= need_big) ? 1 : 0;

    if (big) {
        // overlays (big path only)
        unsigned short* wt_h = (unsigned short*)W_rel;                         // 2MB
        char* wspare = (char*)W_rel + (size_t)2 * 1024 * 1024;
        unsigned short* lwT = (unsigned short*)wspare;                         // 32KB
        unsigned short* xh = (unsigned short*)agg;                             // 5MB
        float* pnorm = (float*)((char*)agg + (size_t)N_NODES * 128 * 2);       // 2.5MB
        int* perm_src = perm;
        // scratch inside msg region (consumed before k_edge_mfma writes msg)
        unsigned short* hps = (unsigned short*)msg;                            // NSEG*N_NODES*2 = 5.12MB
        int* he = (int*)((char*)msg + (size_t)NSEG * N_NODES * 2);             // 2*NSEG*64*4 = 64KB
        int* be = (int*)((char*)he + (size_t)2 * NSEG * 64 * 4);               // 64KB

        k_prep<<<PB_HIST, 256, 0, stream>>>(weight, w_comp, wt_h, loop_w, lwT,
                                            x, xh, etypes, dst, hps, he);
        k_sumseg<<<(N_NODES + 255) / 256, 256, 0, stream>>>(hps, counts2);
        k_scan_all2<<<1, 1024, 0, stream>>>(he, counts2, offsets, off2, be);
        k_scatter3<<<2 * NSEG, 256, 0, stream>>>(etypes, dst, src, norm,
                                                 hps, be, off2, perm_src, pnorm, pos2);
        k_edge_mfma<<<R_REL * NBPR + SELF_B, 256, 0, stream>>>(
            xh, wt_h, lwT, perm_src, pnorm, pos2, offsets, msg, out);
        k_msgsum<<<(N_NODES + 3) / 4, 256, 0, stream>>>(msg, off2, h_bias, out);
    } else {
        k_wrel<<<(R_REL * 16384) / 256, 256, 0, stream>>>(weight, w_comp, W_rel);
        k_zero<<<(N_NODES * 128) / 256, 256, 0, stream>>>(agg, counts, counts2);
        k_hist<<<E_EDGES / 256, 256, 0, stream>>>(etypes, counts);
        k_scan<<<1, 64, 0, stream>>>(counts, offsets, cursor, co);
        k_scatter<<<E_EDGES / 256, 256, 0, stream>>>(etypes, cursor, perm);
        k_edge_atomic<<<E_EDGES / 64 + R_REL, 256, 0, stream>>>(
            x, W_rel, norm, src, dst, perm, offsets, co, agg);
        k_out<<<N_NODES, 128, 0, stream>>>(x, loop_w, agg, h_bias, out);
    }
}

// Round 14
// 252.126 us; speedup vs baseline: 1.0987x; 1.0987x over previous
//
#include <hip/hip_runtime.h>

#define N_NODES 20000
#define E_EDGES 640000
#define R_REL   64
#define B_BASES 16
#define NSEG    128                  // edge segments
#define SEGLEN  (E_EDGES / NSEG)     // 5000
#define RH      10000                // node half-range (LDS histogram bins)
#define NBPR    32                   // blocks per relation in k_edge_mfma
#define QG      ((2 * NSEG) / 16)    // he-entries per scan group = 16

// k_prep block ranges
#define PB_WREL (R_REL * 16)         // 1024 wt_h blocks
#define PB_LW   (PB_WREL + 16)       // +16 lwT blocks
#define PB_XH   (PB_LW + 2500)       // +2500 xhalf blocks (exact)
#define PB_HIST (PB_XH + 2 * NSEG)   // +256 hist blocks

#define SELF_B  ((N_NODES + 63) / 64)   // 313

typedef __attribute__((ext_vector_type(4))) float f32x4;
typedef __attribute__((ext_vector_type(8))) _Float16 half8;

__device__ inline float h2f(unsigned short v) {
    _Float16 h; __builtin_memcpy(&h, &v, 2); return (float)h;
}
__device__ inline unsigned short f2h(float f) {
    _Float16 h = (_Float16)f; unsigned short v; __builtin_memcpy(&v, &h, 2); return v;
}

__device__ inline void gld_lds16(const void* g, void* l) {
    __builtin_amdgcn_global_load_lds(
        (const __attribute__((address_space(1))) void*)g,
        (__attribute__((address_space(3))) void*)l, 16, 0, 0);
}

// ======================= big-path precompute (fused) =======================
// [0,1024): wt_h[r][o][i] = f16(sum_b w_comp[r,b]*weight[b][i][o])
// [1024,1040): lwT[o][i] = f16(loop_w[i][o])
// [1040,3540): xh = f16(x)
// [3540,3796): per-(seg,half) dst hist (ushort) + etype hist
__global__ void k_prep(const float* weight, const float* w_comp, unsigned short* wt_h,
                       const float* lw, unsigned short* lwT,
                       const float* x, unsigned short* xh,
                       const int* etypes, const int* dst,
                       unsigned short* hps, int* he)
{
    __shared__ float tile[32][33];
    __shared__ float wcS[B_BASES];
    __shared__ int lh[RH];
    __shared__ int heL[R_REL];
    int b = blockIdx.x, t = threadIdx.x;
    int tx = t & 31, ty = t >> 5;   // 32 x 8

    if (b < PB_WREL) {
        int r  = b >> 4;
        int ti = (b >> 2) & 3;
        int tj = b & 3;
        if (t < B_BASES) wcS[t] = w_comp[r * B_BASES + t];
        __syncthreads();
        float acc[4] = {0.f, 0.f, 0.f, 0.f};
        const float* wp = weight + (ti * 32) * 128 + tj * 32;
        for (int bb = 0; bb < B_BASES; bb++) {
            float c = wcS[bb];
            #pragma unroll
            for (int s = 0; s < 4; s++)
                acc[s] += c * wp[bb * 16384 + (ty + s * 8) * 128 + tx];
        }
        #pragma unroll
        for (int s = 0; s < 4; s++) tile[ty + s * 8][tx] = acc[s];
        __syncthreads();
        unsigned short* dstp = wt_h + r * 16384 + (tj * 32) * 128 + ti * 32;
        #pragma unroll
        for (int s = 0; s < 4; s++)
            dstp[(ty + s * 8) * 128 + tx] = f2h(tile[tx][ty + s * 8]);
        return;
    }
    if (b < PB_LW) {
        int q = b - PB_WREL;
        int ti = q >> 2, tj = q & 3;
        const float* srcp = lw + (ti * 32) * 128 + tj * 32;
        #pragma unroll
        for (int s = 0; s < 4; s++)
            tile[ty + s * 8][tx] = srcp[(ty + s * 8) * 128 + tx];
        __syncthreads();
        unsigned short* d = lwT + (tj * 32) * 128 + ti * 32;
        #pragma unroll
        for (int s = 0; s < 4; s++)
            d[(ty + s * 8) * 128 + tx] = f2h(tile[tx][ty + s * 8]);
        return;
    }
    if (b < PB_XH) {
        int i4 = (b - PB_LW) * 256 + t;    // exact: 2500*256 = N*128/4
        float4 v = ((const float4*)x)[i4];
        ushort4 o;
        o.x = f2h(v.x); o.y = f2h(v.y); o.z = f2h(v.z); o.w = f2h(v.w);
        ((ushort4*)xh)[i4] = o;
        return;
    }
    // histogram blocks
    {
        int q = b - PB_XH;
        int s = q >> 1, h = q & 1;
        for (int i = t; i < RH; i += 256) lh[i] = 0;
        if (t < R_REL) heL[t] = 0;
        __syncthreads();
        int e0 = s * SEGLEN;
        for (int k = t; k < SEGLEN; k += 256) {
            int e = e0 + k;
            int d = dst[e];
            unsigned ld = (unsigned)(d - h * RH);
            if (ld < RH) {
                atomicAdd(&lh[ld], 1);
                atomicAdd(&heL[etypes[e]], 1);
            }
        }
        __syncthreads();
        for (int i = t; i < RH; i += 256)
            hps[(size_t)s * N_NODES + h * RH + i] = (unsigned short)lh[i];
        if (t < R_REL) he[q * 64 + t] = heL[t];
    }
}

// fused: hps[s][n] -> within-node exclusive prefix (ushort), counts2[n] = total
__global__ void k_sumseg(unsigned short* hps, int* counts2)
{
    int n = blockIdx.x * 256 + threadIdx.x;
    if (n >= N_NODES) return;
    int run = 0;
    for (int q = 0; q < NSEG; q += 8) {
        int v[8];
        #pragma unroll
        for (int k = 0; k < 8; k++) v[k] = hps[(size_t)(q + k) * N_NODES + n];
        #pragma unroll
        for (int k = 0; k < 8; k++) {
            hps[(size_t)(q + k) * N_NODES + n] = (unsigned short)run;
            run += v[k];
        }
    }
    counts2[n] = run;
}

// single block 1024: PARALLEL etype scan + be fill, plus off2 scan (from counts2)
__global__ void k_scan_all2(const int* he, const int* counts2,
                            int* offsets, int* off2, int* be)
{
    __shared__ int part[1024];
    __shared__ int psum[16][R_REL];
    __shared__ int offL[R_REL];
    int tid = threadIdx.x;
    int t = tid & 63;          // etype
    int g = tid >> 6;          // group 0..15
    int vals[QG];
    int ps = 0;
    #pragma unroll
    for (int k = 0; k < QG; k++) {
        vals[k] = he[(g * QG + k) * 64 + t];
        ps += vals[k];
    }
    psum[g][t] = ps;
    __syncthreads();
    if (tid < 64) {
        int c = 0;
        #pragma unroll
        for (int gg = 0; gg < 16; gg++) c += psum[gg][t];
        int s1 = c;
        for (int d = 1; d < 64; d <<= 1) {
            int a1 = __shfl_up(s1, d);
            if (t >= d) s1 += a1;
        }
        offsets[t] = s1 - c;
        offL[t] = s1 - c;
        if (t == 63) offsets[64] = s1;
    }
    __syncthreads();
    {
        int run = offL[t];
        for (int gg = 0; gg < g; gg++) run += psum[gg][t];
        #pragma unroll
        for (int k = 0; k < QG; k++) {
            be[(g * QG + k) * 64 + t] = run;
            run += vals[k];
        }
    }
    int lo_i = tid * 20, hi_i = lo_i + 20;
    if (hi_i > N_NODES) hi_i = N_NODES;
    if (lo_i > N_NODES) lo_i = N_NODES;
    int s = 0;
    for (int i = lo_i; i < hi_i; i++) s += counts2[i];
    part[tid] = s;
    __syncthreads();
    for (int d = 1; d < 1024; d <<= 1) {
        int v = (tid >= d) ? part[tid - d] : 0;
        __syncthreads();
        part[tid] += v;
        __syncthreads();
    }
    int run = part[tid] - s;
    for (int i = lo_i; i < hi_i; i++) {
        off2[i] = run;
        run += counts2[i];
    }
    if (tid == 1023) off2[N_NODES] = run;
}

// per-(seg,half): lbase = off2[n] + pref ; LDS-atomic slot + p assignment
__global__ void k_scatter3(const int* etypes, const int* dst, const int* src, const float* norm,
                           const unsigned short* hps, const int* be, const int* off2,
                           int* perm_src, float* pnorm, int* pos2)
{
    __shared__ int lbase[RH];
    __shared__ int ebase[R_REL];
    int t = threadIdx.x, q = blockIdx.x;
    int s = q >> 1, h = q & 1;
    for (int i = t; i < RH; i += 256)
        lbase[i] = off2[h * RH + i] + (int)hps[(size_t)s * N_NODES + h * RH + i];
    if (t < R_REL) ebase[t] = be[q * 64 + t];
    __syncthreads();
    int e0 = s * SEGLEN;
    for (int k = t; k < SEGLEN; k += 256) {
        int e = e0 + k;
        int d = dst[e];
        unsigned ld = (unsigned)(d - h * RH);
        if (ld < RH) {
            int slot = atomicAdd(&lbase[ld], 1);
            int p = atomicAdd(&ebase[etypes[e]], 1);
            perm_src[p] = src[e];
            pnorm[p] = norm[e];
            pos2[p] = slot;
        }
    }
}

// ---- Phase A (fused): edge blocks [0, R_REL*NBPR) + self blocks after.
//      1 wave = 16 rows x 128 cols, depth-2 pipeline, 16B permuted stores (c'=lr*8+n). ----
__global__ __launch_bounds__(256) void k_edge_mfma(
    const unsigned short* __restrict__ xh, const unsigned short* __restrict__ wt_h,
    const unsigned short* __restrict__ lwT,
    const int* __restrict__ perm_src, const float* __restrict__ pnorm,
    const int* __restrict__ pos2, const int* __restrict__ offsets,
    unsigned short* __restrict__ msg, float* __restrict__ out)
{
    __shared__ __align__(16) char smemW[32768];   // W: [o=128][16 chunks of 8 f16], swizzled
    int t = threadIdx.x, b = blockIdx.x;
    int l = t & 63, w = t >> 6;
    int lg = l >> 4, lr = l & 15;
    const half8* smW = (const half8*)smemW;

    if (b >= R_REL * NBPR) {
        // ---- self-loop tile ----
        int n0 = (b - R_REL * NBPR) * 64;
        #pragma unroll
        for (int it = 0; it < 8; it++) {
            int s = it * 256 + t;
            int o = s >> 4, ch = s & 15;
            int jx = ch ^ (o & 15);
            gld_lds16(lwT + o * 128 + jx * 8, smemW + s * 16);
        }
        int rowA = w * 16 + lr;
        int nA = n0 + rowA; if (nA >= N_NODES) nA = N_NODES - 1;
        const half8* xr = (const half8*)(xh + (size_t)nA * 128);
        half8 avC[4];
        #pragma unroll
        for (int kk = 0; kk < 4; kk++) avC[kk] = xr[kk * 4 + lg];
        f32x4 acc[8];
        #pragma unroll
        for (int n = 0; n < 8; n++) acc[n] = {0.0f, 0.0f, 0.0f, 0.0f};
        __syncthreads();
        #pragma unroll
        for (int kk = 0; kk < 4; kk++) {
            #pragma unroll
            for (int n = 0; n < 8; n++) {
                int o = n * 16 + lr;
                half8 bv = smW[o * 16 + ((kk * 4 + lg) ^ (o & 15))];
                acc[n] = __builtin_amdgcn_mfma_f32_16x16x32_f16(avC[kk], bv, acc[n], 0, 0, 0);
            }
        }
        #pragma unroll
        for (int jj = 0; jj < 4; jj++) {
            int row = w * 16 + lg * 4 + jj;
            int n = n0 + row;
            if (n < N_NODES) {
                float4 v0, v1;
                v0.x = acc[0][jj]; v0.y = acc[1][jj]; v0.z = acc[2][jj]; v0.w = acc[3][jj];
                v1.x = acc[4][jj]; v1.y = acc[5][jj]; v1.z = acc[6][jj]; v1.w = acc[7][jj];
                *(float4*)(out + (size_t)n * 128 + lr * 8) = v0;
                *(float4*)(out + (size_t)n * 128 + lr * 8 + 4) = v1;
            }
        }
        return;
    }

    // ---- edge blocks ----
    int r = b >> 5;              // NBPR = 32
    int j = b & (NBPR - 1);
    int p0 = offsets[r], p1 = offsets[r + 1];
    int nch = (p1 - p0 + 63) >> 6;

    {
        const size_t rbase = (size_t)r * 16384;
        #pragma unroll
        for (int it = 0; it < 8; it++) {
            int s = it * 256 + t;
            int o = s >> 4, ch = s & 15;
            int jx = ch ^ (o & 15);
            gld_lds16(wt_h + rbase + o * 128 + jx * 8, smemW + s * 16);
        }
    }

    int rowA = w * 16 + lr;

    int i = j;
    int sN = 0;
    if (i < nch) {
        int e0 = p0 + i * 64;
        int cnt = p1 - e0; if (cnt > 64) cnt = 64;
        sN = (rowA < cnt) ? perm_src[e0 + rowA] : 0;
    }

    __syncthreads();     // W resident

    half8 avC[4];
    {
        const half8* xr = (const half8*)(xh + (size_t)sN * 128);
        #pragma unroll
        for (int kk = 0; kk < 4; kk++) avC[kk] = xr[kk * 4 + lg];
    }
    int i2 = i + NBPR;
    if (i2 < nch) {
        int e0 = p0 + i2 * 64;
        int cnt = p1 - e0; if (cnt > 64) cnt = 64;
        sN = (rowA < cnt) ? perm_src[e0 + rowA] : 0;
    }

    while (i < nch) {
        int e0 = p0 + i * 64;
        int cnt = p1 - e0; if (cnt > 64) cnt = 64;

        int slotC[4]; float nrmC[4];
        #pragma unroll
        for (int jj = 0; jj < 4; jj++) {
            int row = w * 16 + lg * 4 + jj;
            bool vld = row < cnt;
            slotC[jj] = vld ? pos2[e0 + row] : -1;
            nrmC[jj]  = vld ? pnorm[e0 + row] : 0.0f;
        }

        half8 avN[4];
        {
            const half8* xr = (const half8*)(xh + (size_t)sN * 128);
            #pragma unroll
            for (int kk = 0; kk < 4; kk++) avN[kk] = xr[kk * 4 + lg];
        }
        int i3 = i2 + NBPR;
        if (i3 < nch) {
            int e0n = p0 + i3 * 64;
            int cntn = p1 - e0n; if (cntn > 64) cntn = 64;
            sN = (rowA < cntn) ? perm_src[e0n + rowA] : 0;
        }

        f32x4 acc[8];
        #pragma unroll
        for (int n = 0; n < 8; n++) acc[n] = {0.0f, 0.0f, 0.0f, 0.0f};

        #pragma unroll
        for (int kk = 0; kk < 4; kk++) {
            #pragma unroll
            for (int n = 0; n < 8; n++) {
                int o = n * 16 + lr;
                half8 bv = smW[o * 16 + ((kk * 4 + lg) ^ (o & 15))];
                acc[n] = __builtin_amdgcn_mfma_f32_16x16x32_f16(avC[kk], bv, acc[n], 0, 0, 0);
            }
        }

        #pragma unroll
        for (int jj = 0; jj < 4; jj++) {
            int slot = slotC[jj];
            if (slot >= 0) {
                float nm = nrmC[jj];
                uint4 ov;
                ov.x = (unsigned int)f2h(acc[0][jj] * nm) | ((unsigned int)f2h(acc[1][jj] * nm) << 16);
                ov.y = (unsigned int)f2h(acc[2][jj] * nm) | ((unsigned int)f2h(acc[3][jj] * nm) << 16);
                ov.z = (unsigned int)f2h(acc[4][jj] * nm) | ((unsigned int)f2h(acc[5][jj] * nm) << 16);
                ov.w = (unsigned int)f2h(acc[6][jj] * nm) | ((unsigned int)f2h(acc[7][jj] * nm) << 16);
                *(uint4*)(msg + (size_t)slot * 128 + lr * 8) = ov;
            }
        }

        #pragma unroll
        for (int kk = 0; kk < 4; kk++) avC[kk] = avN[kk];
        i = i2; i2 = i3;
    }
}

// ---- msg reduction: 1 wave per node, no barriers/LDS. Lane c owns permuted cols {2c,2c+1}.
//      Wave reads full 256B msg row per instruction; self-add from permuted out row;
//      in-register un-permute (nc1 = nc0+16); bias + relu; 4B scattered stores. ----
__global__ __launch_bounds__(256) void k_msgsum(const unsigned short* __restrict__ msg,
                                                const int* __restrict__ off2,
                                                const float* __restrict__ bias,
                                                float* __restrict__ out)
{
    int t = threadIdx.x;
    int wv = t >> 6, c = t & 63;
    int n = blockIdx.x * 4 + wv;
    if (n >= N_NODES) return;
    int m0 = off2[n], m1 = off2[n + 1];
    float a0 = 0.0f, a1 = 0.0f;
    int j = m0;
    for (; j + 4 <= m1; j += 4) {
        unsigned v0 = *(const unsigned*)(msg + (size_t)(j + 0) * 128 + c * 2);
        unsigned v1 = *(const unsigned*)(msg + (size_t)(j + 1) * 128 + c * 2);
        unsigned v2 = *(const unsigned*)(msg + (size_t)(j + 2) * 128 + c * 2);
        unsigned v3 = *(const unsigned*)(msg + (size_t)(j + 3) * 128 + c * 2);
        a0 += h2f((unsigned short)(v0 & 0xffff)) + h2f((unsigned short)(v1 & 0xffff))
            + h2f((unsigned short)(v2 & 0xffff)) + h2f((unsigned short)(v3 & 0xffff));
        a1 += h2f((unsigned short)(v0 >> 16)) + h2f((unsigned short)(v1 >> 16))
            + h2f((unsigned short)(v2 >> 16)) + h2f((unsigned short)(v3 >> 16));
    }
    for (; j < m1; j++) {
        unsigned v = *(const unsigned*)(msg + (size_t)j * 128 + c * 2);
        a0 += h2f((unsigned short)(v & 0xffff));
        a1 += h2f((unsigned short)(v >> 16));
    }
    float2 o = *(const float2*)(out + (size_t)n * 128 + c * 2);   // self (permuted)
    a0 += o.x; a1 += o.y;
    int cp0 = c * 2;
    int nc0 = (cp0 & 7) * 16 + (cp0 >> 3);    // natural col; cp1 -> nc0 + 16
    a0 += bias[nc0]; a1 += bias[nc0 + 16];
    if (a0 < 0.0f) a0 = 0.0f;
    if (a1 < 0.0f) a1 = 0.0f;
    // wave-lockstep: all reads of this row (load instrs above) precede these stores
    out[(size_t)n * 128 + nc0]      = a0;
    out[(size_t)n * 128 + nc0 + 16] = a1;
}

// ======================= fallback path (small ws) =======================

__global__ void k_wrel(const float* weight, const float* w_comp, float* W_rel)
{
    int idx = blockIdx.x * 256 + threadIdx.x;
    int r  = idx >> 14;
    int io = idx & 16383;
    float acc = 0.0f;
    for (int b = 0; b < B_BASES; b++)
        acc += w_comp[r * B_BASES + b] * weight[b * 16384 + io];
    W_rel[idx] = acc;
}

__global__ void k_zero(float* agg, int* counts, int* counts2)
{
    int idx = blockIdx.x * 256 + threadIdx.x;
    if (idx < N_NODES * 128) agg[idx] = 0.0f;
    if (idx < R_REL) counts[idx] = 0;
    if (idx < N_NODES) counts2[idx] = 0;
}

__global__ void k_hist(const int* etypes, int* counts)
{
    __shared__ int h[R_REL];
    int t = threadIdx.x;
    if (t < R_REL) h[t] = 0;
    __syncthreads();
    int e = blockIdx.x * 256 + t;
    atomicAdd(&h[etypes[e]], 1);
    __syncthreads();
    if (t < R_REL && h[t] != 0) atomicAdd(&counts[t], h[t]);
}

__global__ void k_scan(const int* counts, int* offsets, int* cursor, int* co)
{
    if (threadIdx.x == 0) {
        int run = 0, c = 0;
        for (int r = 0; r < R_REL; r++) {
            offsets[r] = run; cursor[r] = run; co[r] = c;
            run += counts[r];
            c   += (counts[r] + 63) >> 6;
        }
        offsets[R_REL] = run; co[R_REL] = c;
    }
}

__global__ void k_scatter(const int* etypes, int* cursor, int* perm)
{
    __shared__ int h[R_REL];
    __shared__ int base[R_REL];
    int t = threadIdx.x;
    if (t < R_REL) h[t] = 0;
    __syncthreads();
    int e = blockIdx.x * 256 + t;
    int et = etypes[e];
    int rank = atomicAdd(&h[et], 1);
    __syncthreads();
    if (t < R_REL && h[t] != 0) base[t] = atomicAdd(&cursor[t], h[t]);
    __syncthreads();
    perm[base[et] + rank] = e;
}

__global__ void k_edge_atomic(const float* x, const float* W_rel, const float* norm,
                              const int* src, const int* dst, const int* perm,
                              const int* offsets, const int* co, float* agg)
{
    __shared__ float4 WfS[2048];
    __shared__ float4 xsS[1024];
    __shared__ int coS[R_REL + 1];
    __shared__ int srcS[64], dstS[64];
    __shared__ float normS[64];
    int t = threadIdx.x, bid = blockIdx.x;
    if (t <= R_REL) coS[t] = co[t];
    __syncthreads();
    if (bid >= coS[R_REL]) return;
    int r = 0;
    while (bid >= coS[r + 1]) r++;
    int e0 = offsets[r] + (bid - coS[r]) * 64;
    int cnt = offsets[r + 1] - e0;
    if (cnt > 64) cnt = 64;
    if (t < 64) {
        if (t < cnt) {
            int eid = perm[e0 + t];
            srcS[t] = src[eid]; dstS[t] = dst[eid]; normS[t] = norm[eid];
        } else { srcS[t] = 0; dstS[t] = 0; normS[t] = 0.0f; }
    }
    const float* xsf = (const float*)xsS;
    int q  = t & 31;
    int eb = t >> 5;
    float4 acc[8];
    for (int k = 0; k < 8; k++) { acc[k].x = 0.f; acc[k].y = 0.f; acc[k].z = 0.f; acc[k].w = 0.f; }
    for (int h = 0; h < 2; h++) {
        __syncthreads();
        const float4* Wsrc = (const float4*)(W_rel + r * 16384 + h * 8192);
        for (int p = 0; p < 8; p++) WfS[p * 256 + t] = Wsrc[p * 256 + t];
        for (int p = 0; p < 4; p++) {
            int idx = p * 256 + t;
            int e = idx >> 4, c = idx & 15;
            xsS[idx] = ((const float4*)(x + srcS[e] * 128 + h * 64))[c];
        }
        __syncthreads();
        for (int i = 0; i < 64; i++) {
            float4 wv = WfS[i * 32 + q];
            for (int k = 0; k < 8; k++) {
                float xv = xsf[(eb + 8 * k) * 64 + i];
                acc[k].x += xv * wv.x;
                acc[k].y += xv * wv.y;
                acc[k].z += xv * wv.z;
                acc[k].w += xv * wv.w;
            }
        }
    }
    for (int k = 0; k < 8; k++) {
        int e = eb + 8 * k;
        if (e < cnt) {
            float nrm = normS[e];
            float* row = agg + dstS[e] * 128 + q * 4;
            atomicAdd(row + 0, acc[k].x * nrm);
            atomicAdd(row + 1, acc[k].y * nrm);
            atomicAdd(row + 2, acc[k].z * nrm);
            atomicAdd(row + 3, acc[k].w * nrm);
        }
    }
}

__global__ void k_out(const float* x, const float* loop_w, const float* agg,
                      const float* bias, float* out)
{
    __shared__ float xrow[128];
    int n = blockIdx.x;
    int o = threadIdx.x;
    xrow[o] = x[n * 128 + o];
    __syncthreads();
    float acc = 0.0f;
    for (int i = 0; i < 128; i++)
        acc += xrow[i] * loop_w[i * 128 + o];
    float val = acc + agg[n * 128 + o] + bias[o];
    if (val < 0.0f) val = 0.0f;
    out[n * 128 + o] = val;
}

extern "C" void kernel_launch(void* const* d_in, const int* in_sizes, int n_in,
                              void* d_out, int out_size, void* d_ws, size_t ws_size,
                              hipStream_t stream)
{
    const float* x      = (const float*)d_in[0];
    const float* weight = (const float*)d_in[1];
    const float* w_comp = (const float*)d_in[2];
    const float* h_bias = (const float*)d_in[3];
    const float* loop_w = (const float*)d_in[4];
    const float* norm   = (const float*)d_in[5];
    const int* src    = (const int*)d_in[6];
    const int* dst    = (const int*)d_in[7];
    const int* etypes = (const int*)d_in[8];
    float* out = (float*)d_out;

    char* ws = (char*)d_ws;
    size_t off = 0;
    float* W_rel = (float*)(ws + off); off += (size_t)R_REL * 16384 * 4;      // big: wt_h (2MB) + lwT in 4MB
    float* agg   = (float*)(ws + off); off += (size_t)N_NODES * 128 * 4;      // big: xh (5MB) + pnorm (2.5MB) in 10MB
    int* perm    = (int*)(ws + off);   off += (size_t)E_EDGES * 4;            // big: perm_src
    int* counts  = (int*)(ws + off);   off += 64 * 4;
    int* offsets = (int*)(ws + off);   off += 68 * 4;
    int* cursor  = (int*)(ws + off);   off += 64 * 4;
    int* co      = (int*)(ws + off);   off += 68 * 4;
    int* counts2 = (int*)(ws + off);   off += (size_t)N_NODES * 4;
    int* off2    = (int*)(ws + off);   off += (size_t)(N_NODES + 4) * 4;      // padded to keep 16B align
    int* cursor2 = (int*)(ws + off);   off += (size_t)N_NODES * 4;
    int* pos2    = (int*)(ws + off);   off += (size_t)E_EDGES * 4;
    unsigned short* msg = (unsigned short*)(ws + off);
    size_t need_big = off + (size_t)E_EDGES * 128 * 2;
    int big = (ws_size >= need_big) ? 1 : 0;

    if (big) {
        // overlays (big path only)
        unsigned short* wt_h = (unsigned short*)W_rel;                         // 2MB
        char* wspare = (char*)W_rel + (size_t)2 * 1024 * 1024;
        unsigned short* lwT = (unsigned short*)wspare;                         // 32KB
        unsigned short* xh = (unsigned short*)agg;                             // 5MB
        float* pnorm = (float*)((char*)agg + (size_t)N_NODES * 128 * 2);       // 2.5MB
        int* perm_src = perm;
        // scratch inside msg region (consumed before k_edge_mfma writes msg)
        unsigned short* hps = (unsigned short*)msg;                            // NSEG*N_NODES*2 = 5.12MB
        int* he = (int*)((char*)msg + (size_t)NSEG * N_NODES * 2);             // 2*NSEG*64*4 = 64KB
        int* be = (int*)((char*)he + (size_t)2 * NSEG * 64 * 4);               // 64KB

        k_prep<<<PB_HIST, 256, 0, stream>>>(weight, w_comp, wt_h, loop_w, lwT,
                                            x, xh, etypes, dst, hps, he);
        k_sumseg<<<(N_NODES + 255) / 256, 256, 0, stream>>>(hps, counts2);
        k_scan_all2<<<1, 1024, 0, stream>>>(he, counts2, offsets, off2, be);
        k_scatter3<<<2 * NSEG, 256, 0, stream>>>(etypes, dst, src, norm,
                                                 hps, be, off2, perm_src, pnorm, pos2);
        k_edge_mfma<<<R_REL * NBPR + SELF_B, 256, 0, stream>>>(
            xh, wt_h, lwT, perm_src, pnorm, pos2, offsets, msg, out);
        k_msgsum<<<(N_NODES + 3) / 4, 256, 0, stream>>>(msg, off2, h_bias, out);
    } else {
        k_wrel<<<(R_REL * 16384) / 256, 256, 0, stream>>>(weight, w_comp, W_rel);
        k_zero<<<(N_NODES * 128) / 256, 256, 0, stream>>>(agg, counts, counts2);
        k_hist<<<E_EDGES / 256, 256, 0, stream>>>(etypes, counts);
        k_scan<<<1, 64, 0, stream>>>(counts, offsets, cursor, co);
        k_scatter<<<E_EDGES / 256, 256, 0, stream>>>(etypes, cursor, perm);
        k_edge_atomic<<<E_EDGES / 64 + R_REL, 256, 0, stream>>>(
            x, W_rel, norm, src, dst, perm, offsets, co, agg);
        k_out<<<N_NODES, 128, 0, stream>>>(x, loop_w, agg, h_bias, out);
    }
}